// Round 2
// baseline (5237.108 us; speedup 1.0000x reference)
//
#include <hip/hip_runtime.h>
#include <math.h>

#define N_CH 62
#define NB 128
#define F 32
#define TLEN 128
#define HID 512
#define G3 1536
#define EPER 992
#define NNODE (N_CH * NB)   // 7936
#define ETOT (EPER * NB)    // 126976
#define FT (F * TLEN)       // 4096
#define DIM (N_CH * F)      // 1984
#define MROWS (NB * TLEN)   // 16384

typedef __attribute__((ext_vector_type(8))) short bf16x8;
typedef __attribute__((ext_vector_type(4))) float f32x4;

__device__ __forceinline__ unsigned short f2bf(float f) {
  unsigned u = __float_as_uint(f);
  unsigned r = u + 0x7fffu + ((u >> 16) & 1u);
  return (unsigned short)(r >> 16);
}
__device__ __forceinline__ float sigmoidf_(float x) { return 1.f / (1.f + __expf(-x)); }

__device__ __forceinline__ void gl_lds16(const void* g, void* l) {
  __builtin_amdgcn_global_load_lds(
      (const __attribute__((address_space(1))) unsigned int*)g,
      (__attribute__((address_space(3))) unsigned int*)l, 16, 0, 0);
}

// ---------------- graph preprocessing ----------------
__global__ void k_deg(const int* __restrict__ src, const float* __restrict__ w,
                      float* __restrict__ deg) {
  int e = blockIdx.x * 256 + threadIdx.x;
  if (e < ETOT) atomicAdd(&deg[src[e]], w[e]);
}

__global__ void k_wn(const int* __restrict__ src, const int* __restrict__ dst,
                     const float* __restrict__ w, const float* __restrict__ deg,
                     float* __restrict__ wn) {
  int e = blockIdx.x * 256 + threadIdx.x;
  if (e < ETOT) {
    float ds = deg[src[e]], dd = deg[dst[e]];
    float a = ds > 0.f ? rsqrtf(ds) : 0.f;
    float b = dd > 0.f ? rsqrtf(dd) : 0.f;
    wn[e] = -a * w[e] * b;
  }
}

__global__ void k_adj(const int* __restrict__ src, const int* __restrict__ dst,
                      int* __restrict__ adj_start, int* __restrict__ adj_src,
                      int* __restrict__ adj_j) {
  __shared__ int cnt[N_CH];
  __shared__ int start[N_CH + 1];
  __shared__ int pos[N_CH];
  int tid = threadIdx.x;
  if (tid < N_CH) { cnt[tid] = 0; pos[tid] = 0; }
  __syncthreads();
  for (int j = tid; j < EPER; j += blockDim.x) atomicAdd(&cnt[dst[j]], 1);
  __syncthreads();
  if (tid == 0) {
    int r = 0;
    for (int c = 0; c < N_CH; c++) { start[c] = r; r += cnt[c]; }
    start[N_CH] = r;
  }
  __syncthreads();
  for (int j = tid; j < EPER; j += blockDim.x) {
    int c = dst[j];
    int slot = start[c] + atomicAdd(&pos[c], 1);
    adj_src[slot] = src[j];
    adj_j[slot] = j;
  }
  if (tid <= N_CH) adj_start[tid] = start[tid];
}

// out[n] = sum_{in-edges e of n} wn[e] * in[src(e)]
__global__ __launch_bounds__(256) void k_prop(const float* __restrict__ in,
                                              float* __restrict__ out,
                                              const float* __restrict__ wn,
                                              const int* __restrict__ adj_start,
                                              const int* __restrict__ adj_src,
                                              const int* __restrict__ adj_j) {
  int n = blockIdx.x, b = n / N_CH, c = n % N_CH;
  int tid = threadIdx.x;
  __shared__ int s_src[EPER];
  __shared__ float s_w[EPER];
  int a0 = adj_start[c], d = adj_start[c + 1] - a0;
  for (int i = tid; i < d; i += 256) {
    s_src[i] = adj_src[a0 + i];
    s_w[i] = wn[b * EPER + adj_j[a0 + i]];
  }
  __syncthreads();
  const float* inb = in + (size_t)b * N_CH * FT;
  float4 acc[4];
#pragma unroll
  for (int i = 0; i < 4; i++) acc[i] = make_float4(0.f, 0.f, 0.f, 0.f);
  int e0 = tid * 16;
  for (int q = 0; q < d; q++) {
    const float* p = inb + (size_t)s_src[q] * FT + e0;
    float w = s_w[q];
#pragma unroll
    for (int i = 0; i < 4; i++) {
      float4 v = *(const float4*)&p[i * 4];
      acc[i].x += w * v.x; acc[i].y += w * v.y; acc[i].z += w * v.z; acc[i].w += w * v.w;
    }
  }
  float* ob = out + (size_t)n * FT + e0;
#pragma unroll
  for (int i = 0; i < 4; i++) *(float4*)&ob[i * 4] = acc[i];
}

// Fused: Tx2 = 2*prop(Tx1) - Tx0;  out = Tx0*W0 + Tx1*W1 + Tx2*W2 + b
// LAYER 1: +leakyReLU, fp32 out [N,F,T]. LAYER 2: bf16 out, seq layout [B,T,DIM].
template <int LAYER>
__global__ __launch_bounds__(256) void k_combine(const float* __restrict__ t0src,
                                                 const float* __restrict__ t1src,
                                                 const float* __restrict__ W,
                                                 const float* __restrict__ bias,
                                                 const float* __restrict__ wn,
                                                 const int* __restrict__ adj_start,
                                                 const int* __restrict__ adj_src,
                                                 const int* __restrict__ adj_j,
                                                 void* __restrict__ outv) {
  int n = blockIdx.x, b = n / N_CH, c = n % N_CH;
  int tid = threadIdx.x;
  __shared__ __align__(16) float s0[FT];
  __shared__ __align__(16) float s1[FT];
  __shared__ __align__(16) float s2[FT];
  __shared__ __align__(16) float sWt[3 * 1152];
  __shared__ float sb[F];
  __shared__ int s_src[EPER];
  __shared__ float s_w[EPER];

  int a0 = adj_start[c], d = adj_start[c + 1] - a0;
  for (int i = tid; i < d; i += 256) {
    s_src[i] = adj_src[a0 + i];
    s_w[i] = wn[b * EPER + adj_j[a0 + i]];
  }
  for (int i = tid; i < 3 * F * F; i += 256) {
    int a = i >> 10, r = i & 1023, g = r >> 5, f = r & 31;
    sWt[a * 1152 + g * 36 + f] = W[(a << 10) + (f << 5) + g];
  }
  if (tid < F) sb[tid] = bias[tid];

  int e0 = tid * 16;
  float4 a4[4];
  {
    const float* t0n = t0src + (size_t)n * FT + e0;
    const float* t1n = t1src + (size_t)n * FT + e0;
#pragma unroll
    for (int i = 0; i < 4; i++) {
      a4[i] = *(const float4*)&t0n[i * 4];
      *(float4*)&s0[e0 + i * 4] = a4[i];
      *(float4*)&s1[e0 + i * 4] = *(const float4*)&t1n[i * 4];
    }
  }
  __syncthreads();
  {
    const float* t1b = t1src + (size_t)b * N_CH * FT;
    float4 acc[4];
#pragma unroll
    for (int i = 0; i < 4; i++) acc[i] = make_float4(0.f, 0.f, 0.f, 0.f);
    for (int q = 0; q < d; q++) {
      const float* p = t1b + (size_t)s_src[q] * FT + e0;
      float w = s_w[q];
#pragma unroll
      for (int i = 0; i < 4; i++) {
        float4 v = *(const float4*)&p[i * 4];
        acc[i].x += w * v.x; acc[i].y += w * v.y; acc[i].z += w * v.z; acc[i].w += w * v.w;
      }
    }
#pragma unroll
    for (int i = 0; i < 4; i++) {
      float4 s;
      s.x = 2.f * acc[i].x - a4[i].x;
      s.y = 2.f * acc[i].y - a4[i].y;
      s.z = 2.f * acc[i].z - a4[i].z;
      s.w = 2.f * acc[i].w - a4[i].w;
      *(float4*)&s2[e0 + i * 4] = s;
    }
  }
  __syncthreads();

  int gq = tid >> 5, tq = tid & 31;
  int g0 = gq << 2, t0 = tq << 2;
  float acc[4][4];
#pragma unroll
  for (int i = 0; i < 4; i++)
#pragma unroll
    for (int j = 0; j < 4; j++) acc[i][j] = 0.f;

#pragma unroll
  for (int f0 = 0; f0 < 32; f0 += 4) {
    float4 w0v[4], w1v[4], w2v[4];
#pragma unroll
    for (int gi = 0; gi < 4; gi++) {
      w0v[gi] = *(const float4*)&sWt[0 * 1152 + (g0 + gi) * 36 + f0];
      w1v[gi] = *(const float4*)&sWt[1 * 1152 + (g0 + gi) * 36 + f0];
      w2v[gi] = *(const float4*)&sWt[2 * 1152 + (g0 + gi) * 36 + f0];
    }
#pragma unroll
    for (int ff = 0; ff < 4; ff++) {
      float4 v0 = *(const float4*)&s0[(f0 + ff) * 128 + t0];
      float4 v1 = *(const float4*)&s1[(f0 + ff) * 128 + t0];
      float4 v2 = *(const float4*)&s2[(f0 + ff) * 128 + t0];
#pragma unroll
      for (int gi = 0; gi < 4; gi++) {
        float w0 = ((const float*)&w0v[gi])[ff];
        float w1 = ((const float*)&w1v[gi])[ff];
        float w2 = ((const float*)&w2v[gi])[ff];
        acc[gi][0] += v0.x * w0 + v1.x * w1 + v2.x * w2;
        acc[gi][1] += v0.y * w0 + v1.y * w1 + v2.y * w2;
        acc[gi][2] += v0.z * w0 + v1.z * w1 + v2.z * w2;
        acc[gi][3] += v0.w * w0 + v1.w * w1 + v2.w * w2;
      }
    }
  }

  if (LAYER == 1) {
    float* out = (float*)outv;
#pragma unroll
    for (int gi = 0; gi < 4; gi++) {
      float bb = sb[g0 + gi];
      float4 o;
      o.x = acc[gi][0] + bb; o.x = o.x > 0.f ? o.x : 0.01f * o.x;
      o.y = acc[gi][1] + bb; o.y = o.y > 0.f ? o.y : 0.01f * o.y;
      o.z = acc[gi][2] + bb; o.z = o.z > 0.f ? o.z : 0.01f * o.z;
      o.w = acc[gi][3] + bb; o.w = o.w > 0.f ? o.w : 0.01f * o.w;
      *(float4*)&out[(size_t)n * FT + (g0 + gi) * 128 + t0] = o;
    }
  } else {
    unsigned short* out = (unsigned short*)outv;
#pragma unroll
    for (int tt = 0; tt < 4; tt++) {
      ushort4 o;
      o.x = f2bf(acc[0][tt] + sb[g0 + 0]);
      o.y = f2bf(acc[1][tt] + sb[g0 + 1]);
      o.z = f2bf(acc[2][tt] + sb[g0 + 2]);
      o.w = f2bf(acc[3][tt] + sb[g0 + 3]);
      *(ushort4*)&out[((size_t)(b * TLEN + t0 + tt)) * DIM + c * F + g0] = o;
    }
  }
}

// fp32 -> bf16 elementwise (n multiple of 4)
__global__ void k_cvt(const float* __restrict__ in, unsigned short* __restrict__ out, int n) {
  int i = (blockIdx.x * 256 + threadIdx.x) * 4;
  if (i < n) {
    float4 v = *(const float4*)&in[i];
    ushort4 o;
    o.x = f2bf(v.x); o.y = f2bf(v.y); o.z = f2bf(v.z); o.w = f2bf(v.w);
    *(ushort4*)&out[i] = o;
  }
}

// ---------- bf16 MFMA GEMM: C[m][n] = sum_k A[m][k]*B[n][k] + bias[n] ----------
// A: [MROWS][DIM] bf16, B: [G3][DIM] bf16, C: [MROWS][G3] fp32. 128x128 tile, BK=32.
__global__ __launch_bounds__(256) void k_gemm_mfma(const unsigned short* __restrict__ Aq,
                                                   const unsigned short* __restrict__ Bq,
                                                   const float* __restrict__ bias,
                                                   float* __restrict__ Cmat) {
  __shared__ unsigned short As[4096];  // [128][32]
  __shared__ unsigned short Bs[4096];
  int tid = threadIdx.x;
  int wid = tid >> 6, lane = tid & 63;
  int lr = lane & 15, lk = lane >> 4;
  int m0 = blockIdx.x * 128, n0 = blockIdx.y * 128;
  int wm = (wid & 1) * 64, wn = (wid >> 1) * 64;
  f32x4 zero = {0.f, 0.f, 0.f, 0.f};
  f32x4 acc[4][4];
#pragma unroll
  for (int i = 0; i < 4; i++)
#pragma unroll
    for (int j = 0; j < 4; j++) acc[i][j] = zero;

  int s0 = tid, s1 = tid + 256;
  const unsigned short* ga0 = Aq + (size_t)(m0 + (s0 >> 2)) * DIM + (s0 & 3) * 8;
  const unsigned short* ga1 = Aq + (size_t)(m0 + (s1 >> 2)) * DIM + (s1 & 3) * 8;
  const unsigned short* gb0 = Bq + (size_t)(n0 + (s0 >> 2)) * DIM + (s0 & 3) * 8;
  const unsigned short* gb1 = Bq + (size_t)(n0 + (s1 >> 2)) * DIM + (s1 & 3) * 8;

  for (int k0 = 0; k0 < DIM; k0 += 32) {
    gl_lds16(ga0 + k0, &As[wid * 512]);
    gl_lds16(ga1 + k0, &As[(wid + 4) * 512]);
    gl_lds16(gb0 + k0, &Bs[wid * 512]);
    gl_lds16(gb1 + k0, &Bs[(wid + 4) * 512]);
    __syncthreads();
    bf16x8 a[4], b[4];
#pragma unroll
    for (int mi = 0; mi < 4; mi++)
      a[mi] = *(const bf16x8*)&As[(wm + mi * 16 + lr) * 32 + lk * 8];
#pragma unroll
    for (int ni = 0; ni < 4; ni++)
      b[ni] = *(const bf16x8*)&Bs[(wn + ni * 16 + lr) * 32 + lk * 8];
#pragma unroll
    for (int mi = 0; mi < 4; mi++)
#pragma unroll
      for (int ni = 0; ni < 4; ni++)
        acc[mi][ni] = __builtin_amdgcn_mfma_f32_16x16x32_bf16(a[mi], b[ni], acc[mi][ni], 0, 0, 0);
    __syncthreads();
  }

#pragma unroll
  for (int mi = 0; mi < 4; mi++)
#pragma unroll
    for (int ni = 0; ni < 4; ni++) {
      int row = m0 + wm + mi * 16 + lk * 4;
      int col = n0 + wn + ni * 16 + lr;
      float bv = bias[col];
#pragma unroll
      for (int r = 0; r < 4; r++)
        Cmat[(size_t)(row + r) * G3 + col] = acc[mi][ni][r] + bv;
    }
}

// ---------- GRU step via MFMA: hg = h @ Whh^T; gates; h' ----------
// grid 16 blocks (j-slice of 32 h-cols -> 96 gate rows), 512 thr (8 waves x 16 batches)
__global__ __launch_bounds__(512) void k_gru_mfma(const float* __restrict__ xg,
                                                   const unsigned short* __restrict__ Wb, // [1536][512] bf16
                                                   const float* __restrict__ bhh,
                                                   const float* __restrict__ hf_in,
                                                   const unsigned short* __restrict__ hb_in,
                                                   float* __restrict__ hf_out,
                                                   unsigned short* __restrict__ hb_out,
                                                   int t) {
  int tid = threadIdx.x, wv = tid >> 6, lane = tid & 63;
  int lr = lane & 15, lk = lane >> 4;
  int jh0 = blockIdx.x * 32;
  int mo = wv * 16;  // 16 batches per wave
  f32x4 zero = {0.f, 0.f, 0.f, 0.f};
  f32x4 acc[3][2];
#pragma unroll
  for (int g = 0; g < 3; g++)
#pragma unroll
    for (int nj = 0; nj < 2; nj++) acc[g][nj] = zero;

#pragma unroll 4
  for (int ks = 0; ks < 512; ks += 32) {
    bf16x8 a = *(const bf16x8*)&hb_in[(size_t)(mo + lr) * HID + ks + lk * 8];
#pragma unroll
    for (int g = 0; g < 3; g++)
#pragma unroll
      for (int nj = 0; nj < 2; nj++) {
        bf16x8 b = *(const bf16x8*)&Wb[(size_t)(g * HID + jh0 + nj * 16 + lr) * HID + ks + lk * 8];
        acc[g][nj] = __builtin_amdgcn_mfma_f32_16x16x32_bf16(a, b, acc[g][nj], 0, 0, 0);
      }
  }

#pragma unroll
  for (int nj = 0; nj < 2; nj++) {
    int j = jh0 + nj * 16 + lr;
    float br = bhh[j], bz = bhh[HID + j], bn = bhh[2 * HID + j];
#pragma unroll
    for (int r = 0; r < 4; r++) {
      int b_ = mo + lk * 4 + r;
      size_t xrow = ((size_t)b_ * TLEN + t) * G3;
      float hr = acc[0][nj][r] + br;
      float hz = acc[1][nj][r] + bz;
      float hn = acc[2][nj][r] + bn;
      float xr = xg[xrow + j], xz = xg[xrow + HID + j], xn = xg[xrow + 2 * HID + j];
      float ho = hf_in[(size_t)b_ * HID + j];
      float rr = sigmoidf_(xr + hr);
      float zz = sigmoidf_(xz + hz);
      float nn = tanhf(xn + rr * hn);
      float hnew = (1.f - zz) * nn + zz * ho;
      hf_out[(size_t)b_ * HID + j] = hnew;
      hb_out[(size_t)b_ * HID + j] = f2bf(hnew);
    }
  }
}

__global__ void k_final(const float* __restrict__ h, const float* __restrict__ Wlin,
                        const float* __restrict__ blin, float* __restrict__ out) {
  int b = blockIdx.x;
  int tid = threadIdx.x;
  int o = tid >> 6, lane = tid & 63;
  float acc = 0.f;
  for (int k = lane; k < HID; k += 64) acc += h[(size_t)b * HID + k] * Wlin[o * HID + k];
#pragma unroll
  for (int off = 32; off; off >>= 1) acc += __shfl_down(acc, off);
  if (lane == 0) out[b * 4 + o] = acc + blin[o];
}

extern "C" void kernel_launch(void* const* d_in, const int* in_sizes, int n_in,
                              void* d_out, int out_size, void* d_ws, size_t ws_size,
                              hipStream_t stream) {
  const float* x = (const float*)d_in[0];
  const int* eidx = (const int*)d_in[1];
  const float* ew = (const float*)d_in[2];
  const float* Wc1 = (const float*)d_in[4];
  const float* bc1 = (const float*)d_in[5];
  const float* Wc2 = (const float*)d_in[6];
  const float* bc2 = (const float*)d_in[7];
  const float* Wih = (const float*)d_in[8];
  const float* Whh = (const float*)d_in[9];
  const float* bih = (const float*)d_in[10];
  const float* bhh = (const float*)d_in[11];
  const float* Wlin = (const float*)d_in[12];
  const float* blin = (const float*)d_in[13];
  const int* src = eidx;
  const int* dst = eidx + ETOT;

  const size_t BIGB = (size_t)NNODE * FT * 4;        // 130,023,424
  const size_t SEQB = (size_t)MROWS * DIM * 2;       // 65,011,712
  char* ws = (char*)d_ws;
  float* P = (float*)ws;                             // prop buffer, later xg (100MB)
  float* C = (float*)(ws + BIGB);
  unsigned short* Db = (unsigned short*)(ws + 2 * BIGB);
  char* S = ws + 2 * BIGB + SEQB;
  float* deg = (float*)S;
  float* wn = (float*)(S + 32768);
  int* adj_src = (int*)(S + 540672);
  int* adj_j = (int*)(S + 544768);
  int* adj_start = (int*)(S + 548864);
  unsigned short* Wihb = (unsigned short*)(S + 549376);   // 6,094,848
  unsigned short* Whhb = (unsigned short*)(S + 6644224);  // 1,572,864
  float* hf0 = (float*)(S + 8217088);
  float* hf1 = (float*)(S + 8479232);
  unsigned short* hb0 = (unsigned short*)(S + 8741376);
  unsigned short* hb1 = (unsigned short*)(S + 8872448);
  float* xg = P;

  if (ws_size < 2 * BIGB + SEQB + 9003520) return;

  hipMemsetAsync(deg, 0, 32768, stream);
  hipMemsetAsync(hf0, 0, 262144, stream);
  hipMemsetAsync(hb0, 0, 131072, stream);

  k_deg<<<ETOT / 256, 256, 0, stream>>>(src, ew, deg);
  k_wn<<<ETOT / 256, 256, 0, stream>>>(src, dst, ew, deg, wn);
  k_adj<<<1, 256, 0, stream>>>(src, dst, adj_start, adj_src, adj_j);

  // ChebConv layer 1
  k_prop<<<NNODE, 256, 0, stream>>>(x, P, wn, adj_start, adj_src, adj_j);
  k_combine<1><<<NNODE, 256, 0, stream>>>(x, P, Wc1, bc1, wn, adj_start, adj_src, adj_j, C);
  // ChebConv layer 2 -> bf16 seq [B,T,DIM]
  k_prop<<<NNODE, 256, 0, stream>>>(C, P, wn, adj_start, adj_src, adj_j);
  k_combine<2><<<NNODE, 256, 0, stream>>>(C, P, Wc2, bc2, wn, adj_start, adj_src, adj_j, Db);

  // weight converts
  k_cvt<<<(G3 * DIM / 4 + 255) / 256, 256, 0, stream>>>(Wih, Wihb, G3 * DIM);
  k_cvt<<<(G3 * HID / 4 + 255) / 256, 256, 0, stream>>>(Whh, Whhb, G3 * HID);

  // xg = seq @ Wih^T + bih  (bf16 MFMA, fp32 accum/out)
  dim3 gg(MROWS / 128, G3 / 128);
  k_gemm_mfma<<<gg, 256, 0, stream>>>(Db, Wihb, bih, xg);

  for (int t = 0; t < TLEN; t++) {
    const float* hfi = (t & 1) ? hf1 : hf0;
    float* hfo = (t & 1) ? hf0 : hf1;
    const unsigned short* hbi = (t & 1) ? hb1 : hb0;
    unsigned short* hbo = (t & 1) ? hb0 : hb1;
    k_gru_mfma<<<16, 512, 0, stream>>>(xg, Whhb, bhh, hfi, hbi, hfo, hbo, t);
  }
  // after t=127 (odd) result is in hf0
  k_final<<<NB, 256, 0, stream>>>(hf0, Wlin, blin, (float*)d_out);
}

// Round 3
// 3107.442 us; speedup vs baseline: 1.6853x; 1.6853x over previous
//
#include <hip/hip_runtime.h>
#include <math.h>

#define N_CH 62
#define NB 128
#define F 32
#define TLEN 128
#define HID 512
#define G3 1536
#define EPER 992
#define NNODE (N_CH * NB)   // 7936
#define ETOT (EPER * NB)    // 126976
#define FT (F * TLEN)       // 4096
#define DIM (N_CH * F)      // 1984
#define MROWS (NB * TLEN)   // 16384
#define GRU_BLOCKS 16

typedef __attribute__((ext_vector_type(8))) short bf16x8;
typedef __attribute__((ext_vector_type(4))) float f32x4;

__device__ __forceinline__ unsigned short f2bf(float f) {
  unsigned u = __float_as_uint(f);
  unsigned r = u + 0x7fffu + ((u >> 16) & 1u);
  return (unsigned short)(r >> 16);
}
__device__ __forceinline__ float sigmoidf_(float x) { return 1.f / (1.f + __expf(-x)); }

__device__ __forceinline__ void gl_lds16(const void* g, void* l) {
  __builtin_amdgcn_global_load_lds(
      (const __attribute__((address_space(1))) unsigned int*)g,
      (__attribute__((address_space(3))) unsigned int*)l, 16, 0, 0);
}

// ---------------- graph preprocessing ----------------
__global__ void k_deg(const int* __restrict__ src, const float* __restrict__ w,
                      float* __restrict__ deg) {
  int e = blockIdx.x * 256 + threadIdx.x;
  if (e < ETOT) atomicAdd(&deg[src[e]], w[e]);
}

__global__ void k_wn(const int* __restrict__ src, const int* __restrict__ dst,
                     const float* __restrict__ w, const float* __restrict__ deg,
                     float* __restrict__ wn) {
  int e = blockIdx.x * 256 + threadIdx.x;
  if (e < ETOT) {
    float ds = deg[src[e]], dd = deg[dst[e]];
    float a = ds > 0.f ? rsqrtf(ds) : 0.f;
    float b = dd > 0.f ? rsqrtf(dd) : 0.f;
    wn[e] = -a * w[e] * b;
  }
}

__global__ void k_adj(const int* __restrict__ src, const int* __restrict__ dst,
                      int* __restrict__ adj_start, int* __restrict__ adj_src,
                      int* __restrict__ adj_j) {
  __shared__ int cnt[N_CH];
  __shared__ int start[N_CH + 1];
  __shared__ int pos[N_CH];
  int tid = threadIdx.x;
  if (tid < N_CH) { cnt[tid] = 0; pos[tid] = 0; }
  __syncthreads();
  for (int j = tid; j < EPER; j += blockDim.x) atomicAdd(&cnt[dst[j]], 1);
  __syncthreads();
  if (tid == 0) {
    int r = 0;
    for (int c = 0; c < N_CH; c++) { start[c] = r; r += cnt[c]; }
    start[N_CH] = r;
  }
  __syncthreads();
  for (int j = tid; j < EPER; j += blockDim.x) {
    int c = dst[j];
    int slot = start[c] + atomicAdd(&pos[c], 1);
    adj_src[slot] = src[j];
    adj_j[slot] = j;
  }
  if (tid <= N_CH) adj_start[tid] = start[tid];
}

// out[n] = sum_{in-edges e of n} wn[e] * in[src(e)]
__global__ __launch_bounds__(256) void k_prop(const float* __restrict__ in,
                                              float* __restrict__ out,
                                              const float* __restrict__ wn,
                                              const int* __restrict__ adj_start,
                                              const int* __restrict__ adj_src,
                                              const int* __restrict__ adj_j) {
  int n = blockIdx.x, b = n / N_CH, c = n % N_CH;
  int tid = threadIdx.x;
  __shared__ int s_src[EPER];
  __shared__ float s_w[EPER];
  int a0 = adj_start[c], d = adj_start[c + 1] - a0;
  for (int i = tid; i < d; i += 256) {
    s_src[i] = adj_src[a0 + i];
    s_w[i] = wn[b * EPER + adj_j[a0 + i]];
  }
  __syncthreads();
  const float* inb = in + (size_t)b * N_CH * FT;
  float4 acc[4];
#pragma unroll
  for (int i = 0; i < 4; i++) acc[i] = make_float4(0.f, 0.f, 0.f, 0.f);
  int e0 = tid * 16;
  for (int q = 0; q < d; q++) {
    const float* p = inb + (size_t)s_src[q] * FT + e0;
    float w = s_w[q];
#pragma unroll
    for (int i = 0; i < 4; i++) {
      float4 v = *(const float4*)&p[i * 4];
      acc[i].x += w * v.x; acc[i].y += w * v.y; acc[i].z += w * v.z; acc[i].w += w * v.w;
    }
  }
  float* ob = out + (size_t)n * FT + e0;
#pragma unroll
  for (int i = 0; i < 4; i++) *(float4*)&ob[i * 4] = acc[i];
}

// Fused: Tx2 = 2*prop(Tx1) - Tx0;  out = Tx0*W0 + Tx1*W1 + Tx2*W2 + b
template <int LAYER>
__global__ __launch_bounds__(256) void k_combine(const float* __restrict__ t0src,
                                                 const float* __restrict__ t1src,
                                                 const float* __restrict__ W,
                                                 const float* __restrict__ bias,
                                                 const float* __restrict__ wn,
                                                 const int* __restrict__ adj_start,
                                                 const int* __restrict__ adj_src,
                                                 const int* __restrict__ adj_j,
                                                 void* __restrict__ outv) {
  int n = blockIdx.x, b = n / N_CH, c = n % N_CH;
  int tid = threadIdx.x;
  __shared__ __align__(16) float s0[FT];
  __shared__ __align__(16) float s1[FT];
  __shared__ __align__(16) float s2[FT];
  __shared__ __align__(16) float sWt[3 * 1152];
  __shared__ float sb[F];
  __shared__ int s_src[EPER];
  __shared__ float s_w[EPER];

  int a0 = adj_start[c], d = adj_start[c + 1] - a0;
  for (int i = tid; i < d; i += 256) {
    s_src[i] = adj_src[a0 + i];
    s_w[i] = wn[b * EPER + adj_j[a0 + i]];
  }
  for (int i = tid; i < 3 * F * F; i += 256) {
    int a = i >> 10, r = i & 1023, g = r >> 5, f = r & 31;
    sWt[a * 1152 + g * 36 + f] = W[(a << 10) + (f << 5) + g];
  }
  if (tid < F) sb[tid] = bias[tid];

  int e0 = tid * 16;
  float4 a4[4];
  {
    const float* t0n = t0src + (size_t)n * FT + e0;
    const float* t1n = t1src + (size_t)n * FT + e0;
#pragma unroll
    for (int i = 0; i < 4; i++) {
      a4[i] = *(const float4*)&t0n[i * 4];
      *(float4*)&s0[e0 + i * 4] = a4[i];
      *(float4*)&s1[e0 + i * 4] = *(const float4*)&t1n[i * 4];
    }
  }
  __syncthreads();
  {
    const float* t1b = t1src + (size_t)b * N_CH * FT;
    float4 acc[4];
#pragma unroll
    for (int i = 0; i < 4; i++) acc[i] = make_float4(0.f, 0.f, 0.f, 0.f);
    for (int q = 0; q < d; q++) {
      const float* p = t1b + (size_t)s_src[q] * FT + e0;
      float w = s_w[q];
#pragma unroll
      for (int i = 0; i < 4; i++) {
        float4 v = *(const float4*)&p[i * 4];
        acc[i].x += w * v.x; acc[i].y += w * v.y; acc[i].z += w * v.z; acc[i].w += w * v.w;
      }
    }
#pragma unroll
    for (int i = 0; i < 4; i++) {
      float4 s;
      s.x = 2.f * acc[i].x - a4[i].x;
      s.y = 2.f * acc[i].y - a4[i].y;
      s.z = 2.f * acc[i].z - a4[i].z;
      s.w = 2.f * acc[i].w - a4[i].w;
      *(float4*)&s2[e0 + i * 4] = s;
    }
  }
  __syncthreads();

  int gq = tid >> 5, tq = tid & 31;
  int g0 = gq << 2, t0 = tq << 2;
  float acc[4][4];
#pragma unroll
  for (int i = 0; i < 4; i++)
#pragma unroll
    for (int j = 0; j < 4; j++) acc[i][j] = 0.f;

#pragma unroll
  for (int f0 = 0; f0 < 32; f0 += 4) {
    float4 w0v[4], w1v[4], w2v[4];
#pragma unroll
    for (int gi = 0; gi < 4; gi++) {
      w0v[gi] = *(const float4*)&sWt[0 * 1152 + (g0 + gi) * 36 + f0];
      w1v[gi] = *(const float4*)&sWt[1 * 1152 + (g0 + gi) * 36 + f0];
      w2v[gi] = *(const float4*)&sWt[2 * 1152 + (g0 + gi) * 36 + f0];
    }
#pragma unroll
    for (int ff = 0; ff < 4; ff++) {
      float4 v0 = *(const float4*)&s0[(f0 + ff) * 128 + t0];
      float4 v1 = *(const float4*)&s1[(f0 + ff) * 128 + t0];
      float4 v2 = *(const float4*)&s2[(f0 + ff) * 128 + t0];
#pragma unroll
      for (int gi = 0; gi < 4; gi++) {
        float w0 = ((const float*)&w0v[gi])[ff];
        float w1 = ((const float*)&w1v[gi])[ff];
        float w2 = ((const float*)&w2v[gi])[ff];
        acc[gi][0] += v0.x * w0 + v1.x * w1 + v2.x * w2;
        acc[gi][1] += v0.y * w0 + v1.y * w1 + v2.y * w2;
        acc[gi][2] += v0.z * w0 + v1.z * w1 + v2.z * w2;
        acc[gi][3] += v0.w * w0 + v1.w * w1 + v2.w * w2;
      }
    }
  }

  if (LAYER == 1) {
    float* out = (float*)outv;
#pragma unroll
    for (int gi = 0; gi < 4; gi++) {
      float bb = sb[g0 + gi];
      float4 o;
      o.x = acc[gi][0] + bb; o.x = o.x > 0.f ? o.x : 0.01f * o.x;
      o.y = acc[gi][1] + bb; o.y = o.y > 0.f ? o.y : 0.01f * o.y;
      o.z = acc[gi][2] + bb; o.z = o.z > 0.f ? o.z : 0.01f * o.z;
      o.w = acc[gi][3] + bb; o.w = o.w > 0.f ? o.w : 0.01f * o.w;
      *(float4*)&out[(size_t)n * FT + (g0 + gi) * 128 + t0] = o;
    }
  } else {
    unsigned short* out = (unsigned short*)outv;
#pragma unroll
    for (int tt = 0; tt < 4; tt++) {
      ushort4 o;
      o.x = f2bf(acc[0][tt] + sb[g0 + 0]);
      o.y = f2bf(acc[1][tt] + sb[g0 + 1]);
      o.z = f2bf(acc[2][tt] + sb[g0 + 2]);
      o.w = f2bf(acc[3][tt] + sb[g0 + 3]);
      *(ushort4*)&out[((size_t)(b * TLEN + t0 + tt)) * DIM + c * F + g0] = o;
    }
  }
}

// fp32 -> bf16 elementwise (n multiple of 4)
__global__ void k_cvt(const float* __restrict__ in, unsigned short* __restrict__ out, int n) {
  int i = (blockIdx.x * 256 + threadIdx.x) * 4;
  if (i < n) {
    float4 v = *(const float4*)&in[i];
    ushort4 o;
    o.x = f2bf(v.x); o.y = f2bf(v.y); o.z = f2bf(v.z); o.w = f2bf(v.w);
    *(ushort4*)&out[i] = o;
  }
}

// ---------- bf16 MFMA GEMM: C[m][n] = sum_k A[m][k]*B[n][k] + bias[n] ----------
__global__ __launch_bounds__(256) void k_gemm_mfma(const unsigned short* __restrict__ Aq,
                                                   const unsigned short* __restrict__ Bq,
                                                   const float* __restrict__ bias,
                                                   float* __restrict__ Cmat) {
  __shared__ unsigned short As[4096];  // [128][32]
  __shared__ unsigned short Bs[4096];
  int tid = threadIdx.x;
  int wid = tid >> 6, lane = tid & 63;
  int lr = lane & 15, lk = lane >> 4;
  int m0 = blockIdx.x * 128, n0 = blockIdx.y * 128;
  int wm = (wid & 1) * 64, wn = (wid >> 1) * 64;
  f32x4 zero = {0.f, 0.f, 0.f, 0.f};
  f32x4 acc[4][4];
#pragma unroll
  for (int i = 0; i < 4; i++)
#pragma unroll
    for (int j = 0; j < 4; j++) acc[i][j] = zero;

  int s0 = tid, s1 = tid + 256;
  const unsigned short* ga0 = Aq + (size_t)(m0 + (s0 >> 2)) * DIM + (s0 & 3) * 8;
  const unsigned short* ga1 = Aq + (size_t)(m0 + (s1 >> 2)) * DIM + (s1 & 3) * 8;
  const unsigned short* gb0 = Bq + (size_t)(n0 + (s0 >> 2)) * DIM + (s0 & 3) * 8;
  const unsigned short* gb1 = Bq + (size_t)(n0 + (s1 >> 2)) * DIM + (s1 & 3) * 8;

  for (int k0 = 0; k0 < DIM; k0 += 32) {
    gl_lds16(ga0 + k0, &As[wid * 512]);
    gl_lds16(ga1 + k0, &As[(wid + 4) * 512]);
    gl_lds16(gb0 + k0, &Bs[wid * 512]);
    gl_lds16(gb1 + k0, &Bs[(wid + 4) * 512]);
    __syncthreads();
    bf16x8 a[4], b[4];
#pragma unroll
    for (int mi = 0; mi < 4; mi++)
      a[mi] = *(const bf16x8*)&As[(wm + mi * 16 + lr) * 32 + lk * 8];
#pragma unroll
    for (int ni = 0; ni < 4; ni++)
      b[ni] = *(const bf16x8*)&Bs[(wn + ni * 16 + lr) * 32 + lk * 8];
#pragma unroll
    for (int mi = 0; mi < 4; mi++)
#pragma unroll
      for (int ni = 0; ni < 4; ni++)
        acc[mi][ni] = __builtin_amdgcn_mfma_f32_16x16x32_bf16(a[mi], b[ni], acc[mi][ni], 0, 0, 0);
    __syncthreads();
  }

#pragma unroll
  for (int mi = 0; mi < 4; mi++)
#pragma unroll
    for (int ni = 0; ni < 4; ni++) {
      int row = m0 + wm + mi * 16 + lk * 4;
      int col = n0 + wn + ni * 16 + lr;
      float bv = bias[col];
#pragma unroll
      for (int r = 0; r < 4; r++)
        Cmat[(size_t)(row + r) * G3 + col] = acc[mi][ni][r] + bv;
    }
}

// ---------- persistent GRU: all 128 steps in one kernel ----------
// 16 blocks x 512 thr (8 waves). Block owns 32 h-cols (96 gate rows), W slice in LDS.
// h master fp32 lives in registers; bf16 h exchanged via double-buffered global.
__global__ __launch_bounds__(512, 1) void k_gru_persistent(
    const float* __restrict__ xg,              // [B*T][1536] fp32
    const unsigned short* __restrict__ Wb,     // [1536][512] bf16
    const float* __restrict__ bhh,
    unsigned short* __restrict__ hbA,          // [128][512] bf16, zeroed
    unsigned short* __restrict__ hbB,
    float* __restrict__ hf_out,                // [128][512] fp32 final
    unsigned int* __restrict__ barrier_cnt) {  // zeroed
  __shared__ unsigned short Wlds[96 * 520];    // +8 elem pad: lr-stride 1040B -> 2 lanes/bank
  int tid = threadIdx.x;
  int wv = tid >> 6, lane = tid & 63;
  int lr = lane & 15, lk = lane >> 4;
  int jh0 = blockIdx.x * 32;
  int mo = wv * 16;

  // stage W slice (96 rows x 512) into padded LDS
  for (int i = tid; i < 96 * 64; i += 512) {
    int row = i >> 6, chunk = i & 63;
    int g = row >> 5, jj = row & 31;
    bf16x8 v = *(const bf16x8*)&Wb[(size_t)(g * HID + jh0 + jj) * HID + chunk * 8];
    *(bf16x8*)&Wlds[row * 520 + chunk * 8] = v;
  }
  __syncthreads();

  // hoisted biases: a=0/1 -> col j = jh0 + a*16 + lr
  float br[2], bz[2], bn[2];
#pragma unroll
  for (int a = 0; a < 2; a++) {
    int j = jh0 + a * 16 + lr;
    br[a] = bhh[j]; bz[a] = bhh[HID + j]; bn[a] = bhh[2 * HID + j];
  }

  float hm[2][4];  // fp32 master h: [a][r], b = mo + lk*4 + r
#pragma unroll
  for (int a = 0; a < 2; a++)
#pragma unroll
    for (int r = 0; r < 4; r++) hm[a][r] = 0.f;

  for (int t = 0; t < TLEN; t++) {
    const unsigned short* hin = (t & 1) ? hbB : hbA;
    unsigned short* hout = (t & 1) ? hbA : hbB;

    // prefetch xg for this step (independent of h -> overlaps MFMA)
    float xv[2][4][3];
#pragma unroll
    for (int a = 0; a < 2; a++) {
      int j = jh0 + a * 16 + lr;
#pragma unroll
      for (int r = 0; r < 4; r++) {
        size_t xrow = ((size_t)(mo + lk * 4 + r) * TLEN + t) * G3;
        xv[a][r][0] = xg[xrow + j];
        xv[a][r][1] = xg[xrow + HID + j];
        xv[a][r][2] = xg[xrow + 2 * HID + j];
      }
    }

    f32x4 acc[6];  // n = g*2 + a
#pragma unroll
    for (int n = 0; n < 6; n++) acc[n] = (f32x4){0.f, 0.f, 0.f, 0.f};
#pragma unroll 4
    for (int ks = 0; ks < 16; ks++) {
      bf16x8 av = *(const bf16x8*)&hin[(size_t)(mo + lr) * HID + ks * 32 + lk * 8];
#pragma unroll
      for (int n = 0; n < 6; n++) {
        bf16x8 bv = *(const bf16x8*)&Wlds[((n >> 1) * 32 + (n & 1) * 16 + lr) * 520 + ks * 32 + lk * 8];
        acc[n] = __builtin_amdgcn_mfma_f32_16x16x32_bf16(av, bv, acc[n], 0, 0, 0);
      }
    }

#pragma unroll
    for (int a = 0; a < 2; a++) {
      int j = jh0 + a * 16 + lr;
#pragma unroll
      for (int r = 0; r < 4; r++) {
        int b_ = mo + lk * 4 + r;
        float rr = sigmoidf_(xv[a][r][0] + acc[a][r] + br[a]);
        float zz = sigmoidf_(xv[a][r][1] + acc[2 + a][r] + bz[a]);
        float nn = tanhf(xv[a][r][2] + rr * (acc[4 + a][r] + bn[a]));
        float hnew = (1.f - zz) * nn + zz * hm[a][r];
        hm[a][r] = hnew;
        hout[(size_t)b_ * HID + j] = f2bf(hnew);
      }
    }

    if (t < TLEN - 1) {
      __threadfence();
      __syncthreads();
      if (tid == 0) {
        __hip_atomic_fetch_add(barrier_cnt, 1u, __ATOMIC_ACQ_REL, __HIP_MEMORY_SCOPE_AGENT);
        unsigned target = (unsigned)(t + 1) * GRU_BLOCKS;
        while (__hip_atomic_load(barrier_cnt, __ATOMIC_ACQUIRE, __HIP_MEMORY_SCOPE_AGENT) < target)
          __builtin_amdgcn_s_sleep(2);
      }
      __syncthreads();
      __threadfence();
    }
  }

#pragma unroll
  for (int a = 0; a < 2; a++)
#pragma unroll
    for (int r = 0; r < 4; r++)
      hf_out[(size_t)(mo + lk * 4 + r) * HID + jh0 + a * 16 + lr] = hm[a][r];
}

__global__ void k_final(const float* __restrict__ h, const float* __restrict__ Wlin,
                        const float* __restrict__ blin, float* __restrict__ out) {
  int b = blockIdx.x;
  int tid = threadIdx.x;
  int o = tid >> 6, lane = tid & 63;
  float acc = 0.f;
  for (int k = lane; k < HID; k += 64) acc += h[(size_t)b * HID + k] * Wlin[o * HID + k];
#pragma unroll
  for (int off = 32; off; off >>= 1) acc += __shfl_down(acc, off);
  if (lane == 0) out[b * 4 + o] = acc + blin[o];
}

extern "C" void kernel_launch(void* const* d_in, const int* in_sizes, int n_in,
                              void* d_out, int out_size, void* d_ws, size_t ws_size,
                              hipStream_t stream) {
  const float* x = (const float*)d_in[0];
  const int* eidx = (const int*)d_in[1];
  const float* ew = (const float*)d_in[2];
  const float* Wc1 = (const float*)d_in[4];
  const float* bc1 = (const float*)d_in[5];
  const float* Wc2 = (const float*)d_in[6];
  const float* bc2 = (const float*)d_in[7];
  const float* Wih = (const float*)d_in[8];
  const float* Whh = (const float*)d_in[9];
  const float* bih = (const float*)d_in[10];
  const float* bhh = (const float*)d_in[11];
  const float* Wlin = (const float*)d_in[12];
  const float* blin = (const float*)d_in[13];
  const int* src = eidx;
  const int* dst = eidx + ETOT;

  const size_t BIGB = (size_t)NNODE * FT * 4;        // 130,023,424
  const size_t SEQB = (size_t)MROWS * DIM * 2;       // 65,011,712
  char* ws = (char*)d_ws;
  float* P = (float*)ws;                             // prop buffer, later xg
  float* C = (float*)(ws + BIGB);
  unsigned short* Db = (unsigned short*)(ws + 2 * BIGB);
  char* S = ws + 2 * BIGB + SEQB;
  float* deg = (float*)S;
  float* wn = (float*)(S + 32768);
  int* adj_src = (int*)(S + 540672);
  int* adj_j = (int*)(S + 544768);
  int* adj_start = (int*)(S + 548864);
  unsigned short* Wihb = (unsigned short*)(S + 549376);   // 6,094,848
  unsigned short* Whhb = (unsigned short*)(S + 6644224);  // 1,572,864
  float* hf = (float*)(S + 8217088);                      // 262,144
  unsigned short* hbA = (unsigned short*)(S + 8479232);   // 131,072
  unsigned short* hbB = (unsigned short*)(S + 8610304);   // 131,072
  unsigned int* bcnt = (unsigned int*)(S + 8741376);      // 128
  float* xg = P;

  if (ws_size < 2 * BIGB + SEQB + 8741504) return;

  hipMemsetAsync(deg, 0, 32768, stream);
  hipMemsetAsync(hbA, 0, 131072, stream);
  hipMemsetAsync(bcnt, 0, 128, stream);

  k_deg<<<ETOT / 256, 256, 0, stream>>>(src, ew, deg);
  k_wn<<<ETOT / 256, 256, 0, stream>>>(src, dst, ew, deg, wn);
  k_adj<<<1, 256, 0, stream>>>(src, dst, adj_start, adj_src, adj_j);

  // ChebConv layer 1
  k_prop<<<NNODE, 256, 0, stream>>>(x, P, wn, adj_start, adj_src, adj_j);
  k_combine<1><<<NNODE, 256, 0, stream>>>(x, P, Wc1, bc1, wn, adj_start, adj_src, adj_j, C);
  // ChebConv layer 2 -> bf16 seq [B,T,DIM]
  k_prop<<<NNODE, 256, 0, stream>>>(C, P, wn, adj_start, adj_src, adj_j);
  k_combine<2><<<NNODE, 256, 0, stream>>>(C, P, Wc2, bc2, wn, adj_start, adj_src, adj_j, Db);

  // weight converts
  k_cvt<<<(G3 * DIM / 4 + 255) / 256, 256, 0, stream>>>(Wih, Wihb, G3 * DIM);
  k_cvt<<<(G3 * HID / 4 + 255) / 256, 256, 0, stream>>>(Whh, Whhb, G3 * HID);

  // xg = seq @ Wih^T + bih  (bf16 MFMA, fp32 accum/out)
  dim3 gg(MROWS / 128, G3 / 128);
  k_gemm_mfma<<<gg, 256, 0, stream>>>(Db, Wihb, bih, xg);

  // all 128 GRU steps in one persistent kernel
  k_gru_persistent<<<GRU_BLOCKS, 512, 0, stream>>>(xg, Whhb, bhh, hbA, hbB, hf, bcnt);

  k_final<<<NB, 256, 0, stream>>>(hf, Wlin, blin, (float*)d_out);
}

// Round 4
// 2468.836 us; speedup vs baseline: 2.1213x; 1.2587x over previous
//
#include <hip/hip_runtime.h>
#include <math.h>

#define N_CH 62
#define NB 128
#define F 32
#define TLEN 128
#define HID 512
#define G3 1536
#define EPER 992
#define NNODE (N_CH * NB)   // 7936
#define ETOT (EPER * NB)    // 126976
#define FT (F * TLEN)       // 4096
#define DIM (N_CH * F)      // 1984
#define MROWS (NB * TLEN)   // 16384
#define GRU_BLOCKS 16

typedef __attribute__((ext_vector_type(8))) short bf16x8;
typedef __attribute__((ext_vector_type(4))) float f32x4;

__device__ __forceinline__ unsigned short f2bf(float f) {
  unsigned u = __float_as_uint(f);
  unsigned r = u + 0x7fffu + ((u >> 16) & 1u);
  return (unsigned short)(r >> 16);
}
__device__ __forceinline__ float sigmoidf_(float x) { return 1.f / (1.f + __expf(-x)); }

__device__ __forceinline__ void gl_lds16(const void* g, void* l) {
  __builtin_amdgcn_global_load_lds(
      (const __attribute__((address_space(1))) unsigned int*)g,
      (__attribute__((address_space(3))) unsigned int*)l, 16, 0, 0);
}

// ---------------- graph preprocessing ----------------
__global__ void k_deg(const int* __restrict__ src, const float* __restrict__ w,
                      float* __restrict__ deg) {
  int e = blockIdx.x * 256 + threadIdx.x;
  if (e < ETOT) atomicAdd(&deg[src[e]], w[e]);
}

__global__ void k_wn(const int* __restrict__ src, const int* __restrict__ dst,
                     const float* __restrict__ w, const float* __restrict__ deg,
                     float* __restrict__ wn) {
  int e = blockIdx.x * 256 + threadIdx.x;
  if (e < ETOT) {
    float ds = deg[src[e]], dd = deg[dst[e]];
    float a = ds > 0.f ? rsqrtf(ds) : 0.f;
    float b = dd > 0.f ? rsqrtf(dd) : 0.f;
    wn[e] = -a * w[e] * b;
  }
}

__global__ void k_adj(const int* __restrict__ src, const int* __restrict__ dst,
                      int* __restrict__ adj_start, int* __restrict__ adj_src,
                      int* __restrict__ adj_j) {
  __shared__ int cnt[N_CH];
  __shared__ int start[N_CH + 1];
  __shared__ int pos[N_CH];
  int tid = threadIdx.x;
  if (tid < N_CH) { cnt[tid] = 0; pos[tid] = 0; }
  __syncthreads();
  for (int j = tid; j < EPER; j += blockDim.x) atomicAdd(&cnt[dst[j]], 1);
  __syncthreads();
  if (tid == 0) {
    int r = 0;
    for (int c = 0; c < N_CH; c++) { start[c] = r; r += cnt[c]; }
    start[N_CH] = r;
  }
  __syncthreads();
  for (int j = tid; j < EPER; j += blockDim.x) {
    int c = dst[j];
    int slot = start[c] + atomicAdd(&pos[c], 1);
    adj_src[slot] = src[j];
    adj_j[slot] = j;
  }
  if (tid <= N_CH) adj_start[tid] = start[tid];
}

// out[n] = sum_{in-edges e of n} wn[e] * in[src(e)]
__global__ __launch_bounds__(256) void k_prop(const float* __restrict__ in,
                                              float* __restrict__ out,
                                              const float* __restrict__ wn,
                                              const int* __restrict__ adj_start,
                                              const int* __restrict__ adj_src,
                                              const int* __restrict__ adj_j) {
  int n = blockIdx.x, b = n / N_CH, c = n % N_CH;
  int tid = threadIdx.x;
  __shared__ int s_src[EPER];
  __shared__ float s_w[EPER];
  int a0 = adj_start[c], d = adj_start[c + 1] - a0;
  for (int i = tid; i < d; i += 256) {
    s_src[i] = adj_src[a0 + i];
    s_w[i] = wn[b * EPER + adj_j[a0 + i]];
  }
  __syncthreads();
  const float* inb = in + (size_t)b * N_CH * FT;
  float4 acc[4];
#pragma unroll
  for (int i = 0; i < 4; i++) acc[i] = make_float4(0.f, 0.f, 0.f, 0.f);
  int e0 = tid * 16;
  for (int q = 0; q < d; q++) {
    const float* p = inb + (size_t)s_src[q] * FT + e0;
    float w = s_w[q];
#pragma unroll
    for (int i = 0; i < 4; i++) {
      float4 v = *(const float4*)&p[i * 4];
      acc[i].x += w * v.x; acc[i].y += w * v.y; acc[i].z += w * v.z; acc[i].w += w * v.w;
    }
  }
  float* ob = out + (size_t)n * FT + e0;
#pragma unroll
  for (int i = 0; i < 4; i++) *(float4*)&ob[i * 4] = acc[i];
}

// Fused: Tx2 = 2*prop(Tx1) - Tx0;  out = Tx0*W0 + Tx1*W1 + Tx2*W2 + b
template <int LAYER>
__global__ __launch_bounds__(256) void k_combine(const float* __restrict__ t0src,
                                                 const float* __restrict__ t1src,
                                                 const float* __restrict__ W,
                                                 const float* __restrict__ bias,
                                                 const float* __restrict__ wn,
                                                 const int* __restrict__ adj_start,
                                                 const int* __restrict__ adj_src,
                                                 const int* __restrict__ adj_j,
                                                 void* __restrict__ outv) {
  int n = blockIdx.x, b = n / N_CH, c = n % N_CH;
  int tid = threadIdx.x;
  __shared__ __align__(16) float s0[FT];
  __shared__ __align__(16) float s1[FT];
  __shared__ __align__(16) float s2[FT];
  __shared__ __align__(16) float sWt[3 * 1152];
  __shared__ float sb[F];
  __shared__ int s_src[EPER];
  __shared__ float s_w[EPER];

  int a0 = adj_start[c], d = adj_start[c + 1] - a0;
  for (int i = tid; i < d; i += 256) {
    s_src[i] = adj_src[a0 + i];
    s_w[i] = wn[b * EPER + adj_j[a0 + i]];
  }
  for (int i = tid; i < 3 * F * F; i += 256) {
    int a = i >> 10, r = i & 1023, g = r >> 5, f = r & 31;
    sWt[a * 1152 + g * 36 + f] = W[(a << 10) + (f << 5) + g];
  }
  if (tid < F) sb[tid] = bias[tid];

  int e0 = tid * 16;
  float4 a4[4];
  {
    const float* t0n = t0src + (size_t)n * FT + e0;
    const float* t1n = t1src + (size_t)n * FT + e0;
#pragma unroll
    for (int i = 0; i < 4; i++) {
      a4[i] = *(const float4*)&t0n[i * 4];
      *(float4*)&s0[e0 + i * 4] = a4[i];
      *(float4*)&s1[e0 + i * 4] = *(const float4*)&t1n[i * 4];
    }
  }
  __syncthreads();
  {
    const float* t1b = t1src + (size_t)b * N_CH * FT;
    float4 acc[4];
#pragma unroll
    for (int i = 0; i < 4; i++) acc[i] = make_float4(0.f, 0.f, 0.f, 0.f);
    for (int q = 0; q < d; q++) {
      const float* p = t1b + (size_t)s_src[q] * FT + e0;
      float w = s_w[q];
#pragma unroll
      for (int i = 0; i < 4; i++) {
        float4 v = *(const float4*)&p[i * 4];
        acc[i].x += w * v.x; acc[i].y += w * v.y; acc[i].z += w * v.z; acc[i].w += w * v.w;
      }
    }
#pragma unroll
    for (int i = 0; i < 4; i++) {
      float4 s;
      s.x = 2.f * acc[i].x - a4[i].x;
      s.y = 2.f * acc[i].y - a4[i].y;
      s.z = 2.f * acc[i].z - a4[i].z;
      s.w = 2.f * acc[i].w - a4[i].w;
      *(float4*)&s2[e0 + i * 4] = s;
    }
  }
  __syncthreads();

  int gq = tid >> 5, tq = tid & 31;
  int g0 = gq << 2, t0 = tq << 2;
  float acc[4][4];
#pragma unroll
  for (int i = 0; i < 4; i++)
#pragma unroll
    for (int j = 0; j < 4; j++) acc[i][j] = 0.f;

#pragma unroll
  for (int f0 = 0; f0 < 32; f0 += 4) {
    float4 w0v[4], w1v[4], w2v[4];
#pragma unroll
    for (int gi = 0; gi < 4; gi++) {
      w0v[gi] = *(const float4*)&sWt[0 * 1152 + (g0 + gi) * 36 + f0];
      w1v[gi] = *(const float4*)&sWt[1 * 1152 + (g0 + gi) * 36 + f0];
      w2v[gi] = *(const float4*)&sWt[2 * 1152 + (g0 + gi) * 36 + f0];
    }
#pragma unroll
    for (int ff = 0; ff < 4; ff++) {
      float4 v0 = *(const float4*)&s0[(f0 + ff) * 128 + t0];
      float4 v1 = *(const float4*)&s1[(f0 + ff) * 128 + t0];
      float4 v2 = *(const float4*)&s2[(f0 + ff) * 128 + t0];
#pragma unroll
      for (int gi = 0; gi < 4; gi++) {
        float w0 = ((const float*)&w0v[gi])[ff];
        float w1 = ((const float*)&w1v[gi])[ff];
        float w2 = ((const float*)&w2v[gi])[ff];
        acc[gi][0] += v0.x * w0 + v1.x * w1 + v2.x * w2;
        acc[gi][1] += v0.y * w0 + v1.y * w1 + v2.y * w2;
        acc[gi][2] += v0.z * w0 + v1.z * w1 + v2.z * w2;
        acc[gi][3] += v0.w * w0 + v1.w * w1 + v2.w * w2;
      }
    }
  }

  if (LAYER == 1) {
    float* out = (float*)outv;
#pragma unroll
    for (int gi = 0; gi < 4; gi++) {
      float bb = sb[g0 + gi];
      float4 o;
      o.x = acc[gi][0] + bb; o.x = o.x > 0.f ? o.x : 0.01f * o.x;
      o.y = acc[gi][1] + bb; o.y = o.y > 0.f ? o.y : 0.01f * o.y;
      o.z = acc[gi][2] + bb; o.z = o.z > 0.f ? o.z : 0.01f * o.z;
      o.w = acc[gi][3] + bb; o.w = o.w > 0.f ? o.w : 0.01f * o.w;
      *(float4*)&out[(size_t)n * FT + (g0 + gi) * 128 + t0] = o;
    }
  } else {
    unsigned short* out = (unsigned short*)outv;
#pragma unroll
    for (int tt = 0; tt < 4; tt++) {
      ushort4 o;
      o.x = f2bf(acc[0][tt] + sb[g0 + 0]);
      o.y = f2bf(acc[1][tt] + sb[g0 + 1]);
      o.z = f2bf(acc[2][tt] + sb[g0 + 2]);
      o.w = f2bf(acc[3][tt] + sb[g0 + 3]);
      *(ushort4*)&out[((size_t)(b * TLEN + t0 + tt)) * DIM + c * F + g0] = o;
    }
  }
}

// fp32 -> bf16 elementwise (n multiple of 4)
__global__ void k_cvt(const float* __restrict__ in, unsigned short* __restrict__ out, int n) {
  int i = (blockIdx.x * 256 + threadIdx.x) * 4;
  if (i < n) {
    float4 v = *(const float4*)&in[i];
    ushort4 o;
    o.x = f2bf(v.x); o.y = f2bf(v.y); o.z = f2bf(v.z); o.w = f2bf(v.w);
    *(ushort4*)&out[i] = o;
  }
}

// ---------- bf16 MFMA GEMM: C[m][n] = sum_k A[m][k]*B[n][k] + bias[n] ----------
__global__ __launch_bounds__(256) void k_gemm_mfma(const unsigned short* __restrict__ Aq,
                                                   const unsigned short* __restrict__ Bq,
                                                   const float* __restrict__ bias,
                                                   float* __restrict__ Cmat) {
  __shared__ unsigned short As[4096];  // [128][32]
  __shared__ unsigned short Bs[4096];
  int tid = threadIdx.x;
  int wid = tid >> 6, lane = tid & 63;
  int lr = lane & 15, lk = lane >> 4;
  int m0 = blockIdx.x * 128, n0 = blockIdx.y * 128;
  int wm = (wid & 1) * 64, wn = (wid >> 1) * 64;
  f32x4 zero = {0.f, 0.f, 0.f, 0.f};
  f32x4 acc[4][4];
#pragma unroll
  for (int i = 0; i < 4; i++)
#pragma unroll
    for (int j = 0; j < 4; j++) acc[i][j] = zero;

  int s0 = tid, s1 = tid + 256;
  const unsigned short* ga0 = Aq + (size_t)(m0 + (s0 >> 2)) * DIM + (s0 & 3) * 8;
  const unsigned short* ga1 = Aq + (size_t)(m0 + (s1 >> 2)) * DIM + (s1 & 3) * 8;
  const unsigned short* gb0 = Bq + (size_t)(n0 + (s0 >> 2)) * DIM + (s0 & 3) * 8;
  const unsigned short* gb1 = Bq + (size_t)(n0 + (s1 >> 2)) * DIM + (s1 & 3) * 8;

  for (int k0 = 0; k0 < DIM; k0 += 32) {
    gl_lds16(ga0 + k0, &As[wid * 512]);
    gl_lds16(ga1 + k0, &As[(wid + 4) * 512]);
    gl_lds16(gb0 + k0, &Bs[wid * 512]);
    gl_lds16(gb1 + k0, &Bs[(wid + 4) * 512]);
    __syncthreads();
    bf16x8 a[4], b[4];
#pragma unroll
    for (int mi = 0; mi < 4; mi++)
      a[mi] = *(const bf16x8*)&As[(wm + mi * 16 + lr) * 32 + lk * 8];
#pragma unroll
    for (int ni = 0; ni < 4; ni++)
      b[ni] = *(const bf16x8*)&Bs[(wn + ni * 16 + lr) * 32 + lk * 8];
#pragma unroll
    for (int mi = 0; mi < 4; mi++)
#pragma unroll
      for (int ni = 0; ni < 4; ni++)
        acc[mi][ni] = __builtin_amdgcn_mfma_f32_16x16x32_bf16(a[mi], b[ni], acc[mi][ni], 0, 0, 0);
    __syncthreads();
  }

#pragma unroll
  for (int mi = 0; mi < 4; mi++)
#pragma unroll
    for (int ni = 0; ni < 4; ni++) {
      int row = m0 + wm + mi * 16 + lk * 4;
      int col = n0 + wn + ni * 16 + lr;
      float bv = bias[col];
#pragma unroll
      for (int r = 0; r < 4; r++)
        Cmat[(size_t)(row + r) * G3 + col] = acc[mi][ni][r] + bv;
    }
}

// sc0 sc1 = coherence-point access (cross-XCD visible, no L2 inv/wb needed)
#define LDH(I, OFFS) \
  asm volatile("global_load_dwordx4 %0, %1, off offset:" OFFS " sc0 sc1" \
               : "=v"(av[I]) : "v"(hin_p));
#define STH(VAL, OFFS) \
  asm volatile("global_store_short %0, %1, off offset:" OFFS " sc0 sc1" \
               :: "v"(hout_p), "v"((unsigned)(VAL)) : "memory");

// ---------- persistent GRU: all 128 steps in one kernel ----------
__global__ __launch_bounds__(512, 1) void k_gru_persistent(
    const float* __restrict__ xg,              // [B*T][1536] fp32
    const unsigned short* __restrict__ Wb,     // [1536][512] bf16
    const float* __restrict__ bhh,
    unsigned short* __restrict__ hbA,          // [128][512] bf16, zeroed
    unsigned short* __restrict__ hbB,
    float* __restrict__ hf_out,                // [128][512] fp32 final
    unsigned int* __restrict__ barrier_cnt) {  // zeroed
  __shared__ unsigned short Wlds[96 * 520];
  int tid = threadIdx.x;
  int wv = tid >> 6, lane = tid & 63;
  int lr = lane & 15, lk = lane >> 4;
  int jh0 = blockIdx.x * 32;
  int mo = wv * 16;

  for (int i = tid; i < 96 * 64; i += 512) {
    int row = i >> 6, chunk = i & 63;
    int g = row >> 5, jj = row & 31;
    bf16x8 v = *(const bf16x8*)&Wb[(size_t)(g * HID + jh0 + jj) * HID + chunk * 8];
    *(bf16x8*)&Wlds[row * 520 + chunk * 8] = v;
  }
  __syncthreads();

  float br[2], bz[2], bn[2];
#pragma unroll
  for (int a = 0; a < 2; a++) {
    int j = jh0 + a * 16 + lr;
    br[a] = bhh[j]; bz[a] = bhh[HID + j]; bn[a] = bhh[2 * HID + j];
  }

  float hm[2][4];
#pragma unroll
  for (int a = 0; a < 2; a++)
#pragma unroll
    for (int r = 0; r < 4; r++) hm[a][r] = 0.f;

  // prologue: xg for t=0
  float xv[2][4][3];
#pragma unroll
  for (int a = 0; a < 2; a++) {
    int j = jh0 + a * 16 + lr;
#pragma unroll
    for (int r = 0; r < 4; r++) {
      size_t xrow = ((size_t)(mo + lk * 4 + r) * TLEN + 0) * G3;
      xv[a][r][0] = xg[xrow + j];
      xv[a][r][1] = xg[xrow + HID + j];
      xv[a][r][2] = xg[xrow + 2 * HID + j];
    }
  }

  for (int t = 0; t < TLEN; t++) {
    const unsigned short* hin = (t & 1) ? hbB : hbA;
    unsigned short* hout = (t & 1) ? hbA : hbB;
    const unsigned short* hin_p = hin + (size_t)(mo + lr) * HID + lk * 8;
    unsigned short* hout_p = hout + (size_t)(mo + lk * 4) * HID + jh0 + lr;

    // A) coherent h loads (bypass stale L1/L2)
    bf16x8 av[16];
    LDH(0, "0")    LDH(1, "64")   LDH(2, "128")  LDH(3, "192")
    LDH(4, "256")  LDH(5, "320")  LDH(6, "384")  LDH(7, "448")
    LDH(8, "512")  LDH(9, "576")  LDH(10, "640") LDH(11, "704")
    LDH(12, "768") LDH(13, "832") LDH(14, "896") LDH(15, "960")
    asm volatile("s_waitcnt vmcnt(0)" ::: "memory");
    __builtin_amdgcn_sched_barrier(0);

    // B) prefetch xg for t+1 (plain cached loads; hide under MFMA)
    float xn[2][4][3];
    {
      int tp = (t + 1 < TLEN) ? t + 1 : t;
#pragma unroll
      for (int a = 0; a < 2; a++) {
        int j = jh0 + a * 16 + lr;
#pragma unroll
        for (int r = 0; r < 4; r++) {
          size_t xrow = ((size_t)(mo + lk * 4 + r) * TLEN + tp) * G3;
          xn[a][r][0] = xg[xrow + j];
          xn[a][r][1] = xg[xrow + HID + j];
          xn[a][r][2] = xg[xrow + 2 * HID + j];
        }
      }
    }

    // C) MFMA: hg = h @ Whh_slice^T
    f32x4 acc[6];
#pragma unroll
    for (int n = 0; n < 6; n++) acc[n] = (f32x4){0.f, 0.f, 0.f, 0.f};
#pragma unroll
    for (int ks = 0; ks < 16; ks++) {
#pragma unroll
      for (int n = 0; n < 6; n++) {
        bf16x8 bv = *(const bf16x8*)&Wlds[((n >> 1) * 32 + (n & 1) * 16 + lr) * 520 + ks * 32 + lk * 8];
        acc[n] = __builtin_amdgcn_mfma_f32_16x16x32_bf16(av[ks], bv, acc[n], 0, 0, 0);
      }
    }

    // D) gates
    unsigned hv[2][4];
#pragma unroll
    for (int a = 0; a < 2; a++) {
#pragma unroll
      for (int r = 0; r < 4; r++) {
        float rr = sigmoidf_(xv[a][r][0] + acc[a][r] + br[a]);
        float zz = sigmoidf_(xv[a][r][1] + acc[2 + a][r] + bz[a]);
        float nn = tanhf(xv[a][r][2] + rr * (acc[4 + a][r] + bn[a]));
        float hnew = (1.f - zz) * nn + zz * hm[a][r];
        hm[a][r] = hnew;
        hv[a][r] = f2bf(hnew);
      }
    }

    // E) coherent h stores
    STH(hv[0][0], "0")    STH(hv[0][1], "1024") STH(hv[0][2], "2048") STH(hv[0][3], "3072")
    STH(hv[1][0], "32")   STH(hv[1][1], "1056") STH(hv[1][2], "2080") STH(hv[1][3], "3104")

    if (t < TLEN - 1) {
      // F) release: drain stores, then relaxed agent signal
      asm volatile("s_waitcnt vmcnt(0)" ::: "memory");
      __syncthreads();
      if (tid == 0) {
        __hip_atomic_fetch_add(barrier_cnt, 1u, __ATOMIC_RELAXED, __HIP_MEMORY_SCOPE_AGENT);
        unsigned target = (unsigned)(t + 1) * GRU_BLOCKS;
        while (__hip_atomic_load(barrier_cnt, __ATOMIC_RELAXED, __HIP_MEMORY_SCOPE_AGENT) < target)
          __builtin_amdgcn_s_sleep(1);
      }
      __syncthreads();
    }

#pragma unroll
    for (int a = 0; a < 2; a++)
#pragma unroll
      for (int r = 0; r < 4; r++) {
        xv[a][r][0] = xn[a][r][0];
        xv[a][r][1] = xn[a][r][1];
        xv[a][r][2] = xn[a][r][2];
      }
  }

#pragma unroll
  for (int a = 0; a < 2; a++)
#pragma unroll
    for (int r = 0; r < 4; r++)
      hf_out[(size_t)(mo + lk * 4 + r) * HID + jh0 + a * 16 + lr] = hm[a][r];
}

__global__ void k_final(const float* __restrict__ h, const float* __restrict__ Wlin,
                        const float* __restrict__ blin, float* __restrict__ out) {
  int b = blockIdx.x;
  int tid = threadIdx.x;
  int o = tid >> 6, lane = tid & 63;
  float acc = 0.f;
  for (int k = lane; k < HID; k += 64) acc += h[(size_t)b * HID + k] * Wlin[o * HID + k];
#pragma unroll
  for (int off = 32; off; off >>= 1) acc += __shfl_down(acc, off);
  if (lane == 0) out[b * 4 + o] = acc + blin[o];
}

extern "C" void kernel_launch(void* const* d_in, const int* in_sizes, int n_in,
                              void* d_out, int out_size, void* d_ws, size_t ws_size,
                              hipStream_t stream) {
  const float* x = (const float*)d_in[0];
  const int* eidx = (const int*)d_in[1];
  const float* ew = (const float*)d_in[2];
  const float* Wc1 = (const float*)d_in[4];
  const float* bc1 = (const float*)d_in[5];
  const float* Wc2 = (const float*)d_in[6];
  const float* bc2 = (const float*)d_in[7];
  const float* Wih = (const float*)d_in[8];
  const float* Whh = (const float*)d_in[9];
  const float* bih = (const float*)d_in[10];
  const float* bhh = (const float*)d_in[11];
  const float* Wlin = (const float*)d_in[12];
  const float* blin = (const float*)d_in[13];
  const int* src = eidx;
  const int* dst = eidx + ETOT;

  const size_t BIGB = (size_t)NNODE * FT * 4;        // 130,023,424
  const size_t SEQB = (size_t)MROWS * DIM * 2;       // 65,011,712
  char* ws = (char*)d_ws;
  float* P = (float*)ws;                             // prop buffer, later xg
  float* C = (float*)(ws + BIGB);
  unsigned short* Db = (unsigned short*)(ws + 2 * BIGB);
  char* S = ws + 2 * BIGB + SEQB;
  float* deg = (float*)S;
  float* wn = (float*)(S + 32768);
  int* adj_src = (int*)(S + 540672);
  int* adj_j = (int*)(S + 544768);
  int* adj_start = (int*)(S + 548864);
  unsigned short* Wihb = (unsigned short*)(S + 549376);   // 6,094,848
  unsigned short* Whhb = (unsigned short*)(S + 6644224);  // 1,572,864
  float* hf = (float*)(S + 8217088);                      // 262,144
  unsigned short* hbA = (unsigned short*)(S + 8479232);   // 131,072
  unsigned short* hbB = (unsigned short*)(S + 8610304);   // 131,072
  unsigned int* bcnt = (unsigned int*)(S + 8741376);      // 128
  float* xg = P;

  if (ws_size < 2 * BIGB + SEQB + 8741504) return;

  hipMemsetAsync(deg, 0, 32768, stream);
  hipMemsetAsync(hbA, 0, 131072, stream);
  hipMemsetAsync(bcnt, 0, 128, stream);

  k_deg<<<ETOT / 256, 256, 0, stream>>>(src, ew, deg);
  k_wn<<<ETOT / 256, 256, 0, stream>>>(src, dst, ew, deg, wn);
  k_adj<<<1, 256, 0, stream>>>(src, dst, adj_start, adj_src, adj_j);

  // ChebConv layer 1
  k_prop<<<NNODE, 256, 0, stream>>>(x, P, wn, adj_start, adj_src, adj_j);
  k_combine<1><<<NNODE, 256, 0, stream>>>(x, P, Wc1, bc1, wn, adj_start, adj_src, adj_j, C);
  // ChebConv layer 2 -> bf16 seq [B,T,DIM]
  k_prop<<<NNODE, 256, 0, stream>>>(C, P, wn, adj_start, adj_src, adj_j);
  k_combine<2><<<NNODE, 256, 0, stream>>>(C, P, Wc2, bc2, wn, adj_start, adj_src, adj_j, Db);

  // weight converts
  k_cvt<<<(G3 * DIM / 4 + 255) / 256, 256, 0, stream>>>(Wih, Wihb, G3 * DIM);
  k_cvt<<<(G3 * HID / 4 + 255) / 256, 256, 0, stream>>>(Whh, Whhb, G3 * HID);

  // xg = seq @ Wih^T + bih  (bf16 MFMA, fp32 accum/out)
  dim3 gg(MROWS / 128, G3 / 128);
  k_gemm_mfma<<<gg, 256, 0, stream>>>(Db, Wihb, bih, xg);

  // all 128 GRU steps in one persistent kernel
  k_gru_persistent<<<GRU_BLOCKS, 512, 0, stream>>>(xg, Whhb, bhh, hbA, hbB, hf, bcnt);

  k_final<<<NB, 256, 0, stream>>>(hf, Wlin, blin, (float*)d_out);
}

// Round 6
// 1766.247 us; speedup vs baseline: 2.9651x; 1.3978x over previous
//
#include <hip/hip_runtime.h>
#include <math.h>

#define N_CH 62
#define NB 128
#define F 32
#define TLEN 128
#define HID 512
#define G3 1536
#define EPER 992
#define NNODE (N_CH * NB)   // 7936
#define ETOT (EPER * NB)    // 126976
#define DIM (N_CH * F)      // 1984
#define MROWS (NB * TLEN)   // 16384
#define GRU_BLOCKS 16

typedef __attribute__((ext_vector_type(8))) short bf16x8;
typedef __attribute__((ext_vector_type(4))) float f32x4;

__device__ __forceinline__ unsigned short f2bf(float f) {
  unsigned u = __float_as_uint(f);
  unsigned r = u + 0x7fffu + ((u >> 16) & 1u);
  return (unsigned short)(r >> 16);
}
__device__ __forceinline__ float bf2f(unsigned short u) {
  return __uint_as_float(((unsigned)u) << 16);
}
__device__ __forceinline__ float sigmoidf_(float x) { return 1.f / (1.f + __expf(-x)); }

__device__ __forceinline__ void gl_lds16(const void* g, void* l) {
  __builtin_amdgcn_global_load_lds(
      (const __attribute__((address_space(1))) unsigned int*)g,
      (__attribute__((address_space(3))) unsigned int*)l, 16, 0, 0);
}

// ---------------- graph preprocessing ----------------
__global__ void k_deg(const int* __restrict__ src, const float* __restrict__ w,
                      float* __restrict__ deg) {
  int e = blockIdx.x * 256 + threadIdx.x;
  if (e < ETOT) atomicAdd(&deg[src[e]], w[e]);
}

__global__ void k_wn(const int* __restrict__ src, const int* __restrict__ dst,
                     const float* __restrict__ w, const float* __restrict__ deg,
                     float* __restrict__ wn) {
  int e = blockIdx.x * 256 + threadIdx.x;
  if (e < ETOT) {
    float ds = deg[src[e]], dd = deg[dst[e]];
    float a = ds > 0.f ? rsqrtf(ds) : 0.f;
    float b = dd > 0.f ? rsqrtf(dd) : 0.f;
    wn[e] = -a * w[e] * b;
  }
}

// dense per-graph L: L[b][dst][src] (64x64 padded, fp32, zero-initialized)
__global__ void k_ldense(const int* __restrict__ src, const int* __restrict__ dst,
                         const float* __restrict__ wn, float* __restrict__ Lf) {
  int e = blockIdx.x * 256 + threadIdx.x;
  if (e < ETOT) {
    int b = e / EPER;
    int s = src[e] - b * N_CH;
    int d = dst[e] - b * N_CH;
    atomicAdd(&Lf[(size_t)b * 4096 + d * 64 + s], wn[e]);
  }
}

// per graph: M2 = 2*L@L - I (bf16), Lb = bf16(L)
__global__ __launch_bounds__(256) void k_m2(const float* __restrict__ Lf,
                                            unsigned short* __restrict__ Lbf,
                                            unsigned short* __restrict__ M2bf) {
  int b = blockIdx.x, tid = threadIdx.x;
  __shared__ float Ls[4096];
  for (int i = tid; i < 4096; i += 256) Ls[i] = Lf[(size_t)b * 4096 + i];
  __syncthreads();
  for (int h = 0; h < 16; h++) {
    int i = h * 256 + tid;
    int d = i >> 6, s = i & 63;
    float m = 0.f;
#pragma unroll 8
    for (int k = 0; k < 64; k++) m += Ls[d * 64 + k] * Ls[k * 64 + s];
    M2bf[(size_t)b * 4096 + i] = f2bf(2.f * m - (d == s ? 1.f : 0.f));
    Lbf[(size_t)b * 4096 + i] = f2bf(Ls[i]);
  }
}

// x [7936][32][128] fp32 -> Xt0 [128 graphs][4096 rows=(t*32+f)][64 nodes] bf16 (pad n 62..63 = 0)
__global__ __launch_bounds__(256) void k_xt(const float* __restrict__ x,
                                            unsigned short* __restrict__ Xt0) {
  int b = blockIdx.x >> 5, f = blockIdx.x & 31;
  int tid = threadIdx.x;
  for (int u = tid; u < 1024; u += 256) {  // 128 t x 8 chunks
    int t = u >> 3, ch = u & 7;
    unsigned short o[8];
#pragma unroll
    for (int j = 0; j < 8; j++) {
      int n = ch * 8 + j;
      float v = (n < N_CH) ? x[((size_t)(b * N_CH + n) * F + f) * TLEN + t] : 0.f;
      o[j] = f2bf(v);
    }
    *(uint4*)&Xt0[((size_t)b * 4096 + t * 32 + f) * 64 + ch * 8] = *(uint4*)o;
  }
}

// -------- fused ChebConv layer: P1 = Z@L^T, P2 = Z@M2^T (MFMA), einsum combine (VALU) -------
// tile = (graph b, 4 t-values) -> 128 rows x 64 nodes. LDS Z0/P1/P2 swizzled (T2).
template <int LAYER>
__global__ __launch_bounds__(256) void k_cheb(const unsigned short* __restrict__ Xt,
                                              const unsigned short* __restrict__ Lbg,
                                              const unsigned short* __restrict__ M2g,
                                              const float* __restrict__ W,
                                              const float* __restrict__ bias,
                                              void* __restrict__ outv) {
  int b = blockIdx.x >> 5, ts = blockIdx.x & 31;
  int tid = threadIdx.x;
  int wid = tid >> 6, lane = tid & 63;
  int lr = lane & 15, lk = lane >> 4;
  __shared__ unsigned short Z0[128 * 64];
  __shared__ unsigned short P1[128 * 64];
  __shared__ unsigned short P2[128 * 64];

  const size_t tile_base = ((size_t)b * 4096 + ts * 128) * 64;  // elems

  // stage Z0 tile (16KB) via global_load_lds, source pre-swizzled (chunk ^= row&7)
#pragma unroll
  for (int h = 0; h < 4; h++) {
    int p = h * 256 + tid;
    int row = p >> 3, c = (p & 7) ^ (row & 7);
    gl_lds16(Xt + tile_base + (size_t)row * 64 + c * 8,
             &Z0[(h * 256 + wid * 64) * 8]);
  }
  __syncthreads();

  // MFMA: per wave rows [wid*32, wid*32+32)
  f32x4 acc1[2][4], acc2[2][4];
#pragma unroll
  for (int mt = 0; mt < 2; mt++)
#pragma unroll
    for (int nt = 0; nt < 4; nt++) {
      acc1[mt][nt] = (f32x4){0.f, 0.f, 0.f, 0.f};
      acc2[mt][nt] = (f32x4){0.f, 0.f, 0.f, 0.f};
    }
  const unsigned short* Lbb = Lbg + (size_t)b * 4096;
  const unsigned short* Mbb = M2g + (size_t)b * 4096;
#pragma unroll
  for (int kk = 0; kk < 2; kk++) {
    bf16x8 af[2];
#pragma unroll
    for (int mt = 0; mt < 2; mt++) {
      int row = wid * 32 + mt * 16 + lr;
      af[mt] = *(const bf16x8*)&Z0[row * 64 + ((((kk << 2) + lk) ^ (row & 7)) << 3)];
    }
#pragma unroll
    for (int nt = 0; nt < 4; nt++) {
      int brow = nt * 16 + lr;
      bf16x8 bL = *(const bf16x8*)&Lbb[brow * 64 + kk * 32 + lk * 8];
      bf16x8 bM = *(const bf16x8*)&Mbb[brow * 64 + kk * 32 + lk * 8];
#pragma unroll
      for (int mt = 0; mt < 2; mt++) {
        acc1[mt][nt] = __builtin_amdgcn_mfma_f32_16x16x32_bf16(af[mt], bL, acc1[mt][nt], 0, 0, 0);
        acc2[mt][nt] = __builtin_amdgcn_mfma_f32_16x16x32_bf16(af[mt], bM, acc2[mt][nt], 0, 0, 0);
      }
    }
  }
  // write P1/P2 to LDS (swizzled, bf16)
#pragma unroll
  for (int mt = 0; mt < 2; mt++)
#pragma unroll
    for (int nt = 0; nt < 4; nt++) {
      int n = nt * 16 + lr;
#pragma unroll
      for (int r = 0; r < 4; r++) {
        int row = wid * 32 + mt * 16 + lk * 4 + r;
        int elem = row * 64 + ((((n >> 3) ^ (row & 7)) << 3)) + (n & 7);
        P1[elem] = f2bf(acc1[mt][nt][r]);
        P2[elem] = f2bf(acc2[mt][nt][r]);
      }
    }
  __syncthreads();

  // einsum: thread owns (tl, n); acc over f with W via uniform scalar loads
  int tl = tid >> 6, n = tid & 63;
  float acc[32];
#pragma unroll
  for (int g = 0; g < 32; g++) acc[g] = bias[g];
#pragma unroll 4
  for (int f = 0; f < 32; f++) {
    int row = tl * 32 + f;
    int elem = row * 64 + ((((n >> 3) ^ (row & 7)) << 3)) + (n & 7);
    float z0 = bf2f(Z0[elem]);
    float p1 = bf2f(P1[elem]);
    float p2 = bf2f(P2[elem]);
#pragma unroll
    for (int g = 0; g < 32; g++) {
      acc[g] += z0 * W[f * 32 + g] + p1 * W[1024 + f * 32 + g] + p2 * W[2048 + f * 32 + g];
    }
  }

  if (LAYER == 1) {
    unsigned short* out = (unsigned short*)outv;
    unsigned short* dst = out + tile_base + (size_t)(tl * 32) * 64 + n;
#pragma unroll
    for (int g = 0; g < 32; g++) {
      float y = acc[g];
      y = y > 0.f ? y : 0.01f * y;
      dst[g * 64] = f2bf(y);
    }
  } else {
    if (n < N_CH) {
      unsigned uu[16];
#pragma unroll
      for (int q = 0; q < 16; q++)
        uu[q] = (unsigned)f2bf(acc[2 * q]) | ((unsigned)f2bf(acc[2 * q + 1]) << 16);
      unsigned short* dst = (unsigned short*)outv +
                            ((size_t)(b * TLEN + ts * 4 + tl)) * DIM + n * F;
#pragma unroll
      for (int q = 0; q < 4; q++)
        *(uint4*)(dst + q * 8) = *(uint4*)&uu[q * 4];   // FIX: stride 8 shorts (=1 uint4), was 16
    }
  }
}

// fp32 -> bf16 elementwise (n multiple of 4)
__global__ void k_cvt(const float* __restrict__ in, unsigned short* __restrict__ out, int n) {
  int i = (blockIdx.x * 256 + threadIdx.x) * 4;
  if (i < n) {
    float4 v = *(const float4*)&in[i];
    ushort4 o;
    o.x = f2bf(v.x); o.y = f2bf(v.y); o.z = f2bf(v.z); o.w = f2bf(v.w);
    *(ushort4*)&out[i] = o;
  }
}

// ---------- bf16 MFMA GEMM: C[m][n] = sum_k A[m][k]*B[n][k] + bias[n] ----------
__global__ __launch_bounds__(256) void k_gemm_mfma(const unsigned short* __restrict__ Aq,
                                                   const unsigned short* __restrict__ Bq,
                                                   const float* __restrict__ bias,
                                                   float* __restrict__ Cmat) {
  __shared__ unsigned short As[4096];  // [128][32]
  __shared__ unsigned short Bs[4096];
  int tid = threadIdx.x;
  int wid = tid >> 6, lane = tid & 63;
  int lr = lane & 15, lk = lane >> 4;
  int m0 = blockIdx.x * 128, n0 = blockIdx.y * 128;
  int wm = (wid & 1) * 64, wn = (wid >> 1) * 64;
  f32x4 zero = {0.f, 0.f, 0.f, 0.f};
  f32x4 acc[4][4];
#pragma unroll
  for (int i = 0; i < 4; i++)
#pragma unroll
    for (int j = 0; j < 4; j++) acc[i][j] = zero;

  int s0 = tid, s1 = tid + 256;
  const unsigned short* ga0 = Aq + (size_t)(m0 + (s0 >> 2)) * DIM + (s0 & 3) * 8;
  const unsigned short* ga1 = Aq + (size_t)(m0 + (s1 >> 2)) * DIM + (s1 & 3) * 8;
  const unsigned short* gb0 = Bq + (size_t)(n0 + (s0 >> 2)) * DIM + (s0 & 3) * 8;
  const unsigned short* gb1 = Bq + (size_t)(n0 + (s1 >> 2)) * DIM + (s1 & 3) * 8;

  for (int k0 = 0; k0 < DIM; k0 += 32) {
    gl_lds16(ga0 + k0, &As[wid * 512]);
    gl_lds16(ga1 + k0, &As[(wid + 4) * 512]);
    gl_lds16(gb0 + k0, &Bs[wid * 512]);
    gl_lds16(gb1 + k0, &Bs[(wid + 4) * 512]);
    __syncthreads();
    bf16x8 a[4], b[4];
#pragma unroll
    for (int mi = 0; mi < 4; mi++)
      a[mi] = *(const bf16x8*)&As[(wm + mi * 16 + lr) * 32 + lk * 8];
#pragma unroll
    for (int ni = 0; ni < 4; ni++)
      b[ni] = *(const bf16x8*)&Bs[(wn + ni * 16 + lr) * 32 + lk * 8];
#pragma unroll
    for (int mi = 0; mi < 4; mi++)
#pragma unroll
      for (int ni = 0; ni < 4; ni++)
        acc[mi][ni] = __builtin_amdgcn_mfma_f32_16x16x32_bf16(a[mi], b[ni], acc[mi][ni], 0, 0, 0);
    __syncthreads();
  }

#pragma unroll
  for (int mi = 0; mi < 4; mi++)
#pragma unroll
    for (int ni = 0; ni < 4; ni++) {
      int row = m0 + wm + mi * 16 + lk * 4;
      int col = n0 + wn + ni * 16 + lr;
      float bv = bias[col];
#pragma unroll
      for (int r = 0; r < 4; r++)
        Cmat[(size_t)(row + r) * G3 + col] = acc[mi][ni][r] + bv;
    }
}

// sc0 sc1 = coherence-point access (cross-XCD visible, no L2 inv/wb needed)
#define LDH(I, OFFS) \
  asm volatile("global_load_dwordx4 %0, %1, off offset:" OFFS " sc0 sc1" \
               : "=v"(av[I]) : "v"(hin_p));
#define STH(VAL, OFFS) \
  asm volatile("global_store_short %0, %1, off offset:" OFFS " sc0 sc1" \
               :: "v"(hout_p), "v"((unsigned)(VAL)) : "memory");

// ---------- persistent GRU: all 128 steps in one kernel ----------
__global__ __launch_bounds__(512, 1) void k_gru_persistent(
    const float* __restrict__ xg,              // [B*T][1536] fp32
    const unsigned short* __restrict__ Wb,     // [1536][512] bf16
    const float* __restrict__ bhh,
    unsigned short* __restrict__ hbA,          // [128][512] bf16, zeroed
    unsigned short* __restrict__ hbB,
    float* __restrict__ hf_out,                // [128][512] fp32 final
    unsigned int* __restrict__ flags) {        // 16 x 16 uints, zeroed
  __shared__ unsigned short Wlds[96 * 520];
  int tid = threadIdx.x;
  int wv = tid >> 6, lane = tid & 63;
  int lr = lane & 15, lk = lane >> 4;
  int jh0 = blockIdx.x * 32;
  int mo = wv * 16;

  for (int i = tid; i < 96 * 64; i += 512) {
    int row = i >> 6, chunk = i & 63;
    int g = row >> 5, jj = row & 31;
    bf16x8 v = *(const bf16x8*)&Wb[(size_t)(g * HID + jh0 + jj) * HID + chunk * 8];
    *(bf16x8*)&Wlds[row * 520 + chunk * 8] = v;
  }
  __syncthreads();

  float br[2], bz[2], bn[2];
#pragma unroll
  for (int a = 0; a < 2; a++) {
    int j = jh0 + a * 16 + lr;
    br[a] = bhh[j]; bz[a] = bhh[HID + j]; bn[a] = bhh[2 * HID + j];
  }

  float hm[2][4];
#pragma unroll
  for (int a = 0; a < 2; a++)
#pragma unroll
    for (int r = 0; r < 4; r++) hm[a][r] = 0.f;

  // prologue: xg for t=0
  float xv[2][4][3];
#pragma unroll
  for (int a = 0; a < 2; a++) {
    int j = jh0 + a * 16 + lr;
#pragma unroll
    for (int r = 0; r < 4; r++) {
      size_t xrow = ((size_t)(mo + lk * 4 + r) * TLEN + 0) * G3;
      xv[a][r][0] = xg[xrow + j];
      xv[a][r][1] = xg[xrow + HID + j];
      xv[a][r][2] = xg[xrow + 2 * HID + j];
    }
  }

  int fidx = (lane & 15) * 16;

  for (int t = 0; t < TLEN; t++) {
    const unsigned short* hin = (t & 1) ? hbB : hbA;
    unsigned short* hout = (t & 1) ? hbA : hbB;
    const unsigned short* hin_p = hin + (size_t)(mo + lr) * HID + lk * 8;
    unsigned short* hout_p = hout + (size_t)(mo + lk * 4) * HID + jh0 + lr;

    // A) coherent h loads
    bf16x8 av[16];
    LDH(0, "0")    LDH(1, "64")   LDH(2, "128")  LDH(3, "192")
    LDH(4, "256")  LDH(5, "320")  LDH(6, "384")  LDH(7, "448")
    LDH(8, "512")  LDH(9, "576")  LDH(10, "640") LDH(11, "704")
    LDH(12, "768") LDH(13, "832") LDH(14, "896") LDH(15, "960")
    asm volatile("s_waitcnt vmcnt(0)" ::: "memory");
    __builtin_amdgcn_sched_barrier(0);

    // B) MFMA: hg = h @ Whh_slice^T
    f32x4 acc[6];
#pragma unroll
    for (int n = 0; n < 6; n++) acc[n] = (f32x4){0.f, 0.f, 0.f, 0.f};
#pragma unroll
    for (int ks = 0; ks < 16; ks++) {
#pragma unroll
      for (int n = 0; n < 6; n++) {
        bf16x8 bv = *(const bf16x8*)&Wlds[((n >> 1) * 32 + (n & 1) * 16 + lr) * 520 + ks * 32 + lk * 8];
        acc[n] = __builtin_amdgcn_mfma_f32_16x16x32_bf16(av[ks], bv, acc[n], 0, 0, 0);
      }
    }

    // C) gates
    unsigned hv[2][4];
#pragma unroll
    for (int a = 0; a < 2; a++) {
#pragma unroll
      for (int r = 0; r < 4; r++) {
        float rr = sigmoidf_(xv[a][r][0] + acc[a][r] + br[a]);
        float zz = sigmoidf_(xv[a][r][1] + acc[2 + a][r] + bz[a]);
        float nn = tanhf(xv[a][r][2] + rr * (acc[4 + a][r] + bn[a]));
        float hnew = (1.f - zz) * nn + zz * hm[a][r];
        hm[a][r] = hnew;
        hv[a][r] = f2bf(hnew);
      }
    }

    // D) coherent h stores
    STH(hv[0][0], "0")    STH(hv[0][1], "1024") STH(hv[0][2], "2048") STH(hv[0][3], "3072")
    STH(hv[1][0], "32")   STH(hv[1][1], "1056") STH(hv[1][2], "2080") STH(hv[1][3], "3104")

    if (t < TLEN - 1) {
      // E) drain stores, publish flag, prefetch next xg during spin, poll all-wave
      asm volatile("s_waitcnt vmcnt(0)" ::: "memory");
      __syncthreads();
      if (tid == 0)
        __hip_atomic_store(&flags[blockIdx.x * 16], (unsigned)(t + 1),
                           __ATOMIC_RELAXED, __HIP_MEMORY_SCOPE_AGENT);

      float xn[2][4][3];
#pragma unroll
      for (int a = 0; a < 2; a++) {
        int j = jh0 + a * 16 + lr;
#pragma unroll
        for (int r = 0; r < 4; r++) {
          size_t xrow = ((size_t)(mo + lk * 4 + r) * TLEN + (t + 1)) * G3;
          xn[a][r][0] = xg[xrow + j];
          xn[a][r][1] = xg[xrow + HID + j];
          xn[a][r][2] = xg[xrow + 2 * HID + j];
        }
      }

      unsigned tgt = (unsigned)(t + 1);
      while (true) {
        unsigned v = __hip_atomic_load(&flags[fidx], __ATOMIC_RELAXED, __HIP_MEMORY_SCOPE_AGENT);
        if (__ballot(v >= tgt) == ~0ull) break;
        __builtin_amdgcn_s_sleep(0);
      }

#pragma unroll
      for (int a = 0; a < 2; a++)
#pragma unroll
        for (int r = 0; r < 4; r++) {
          xv[a][r][0] = xn[a][r][0];
          xv[a][r][1] = xn[a][r][1];
          xv[a][r][2] = xn[a][r][2];
        }
    }
  }

#pragma unroll
  for (int a = 0; a < 2; a++)
#pragma unroll
    for (int r = 0; r < 4; r++)
      hf_out[(size_t)(mo + lk * 4 + r) * HID + jh0 + a * 16 + lr] = hm[a][r];
}

__global__ void k_final(const float* __restrict__ h, const float* __restrict__ Wlin,
                        const float* __restrict__ blin, float* __restrict__ out) {
  int b = blockIdx.x;
  int tid = threadIdx.x;
  int o = tid >> 6, lane = tid & 63;
  float acc = 0.f;
  for (int k = lane; k < HID; k += 64) acc += h[(size_t)b * HID + k] * Wlin[o * HID + k];
#pragma unroll
  for (int off = 32; off; off >>= 1) acc += __shfl_down(acc, off);
  if (lane == 0) out[b * 4 + o] = acc + blin[o];
}

extern "C" void kernel_launch(void* const* d_in, const int* in_sizes, int n_in,
                              void* d_out, int out_size, void* d_ws, size_t ws_size,
                              hipStream_t stream) {
  const float* x = (const float*)d_in[0];
  const int* eidx = (const int*)d_in[1];
  const float* ew = (const float*)d_in[2];
  const float* Wc1 = (const float*)d_in[4];
  const float* bc1 = (const float*)d_in[5];
  const float* Wc2 = (const float*)d_in[6];
  const float* bc2 = (const float*)d_in[7];
  const float* Wih = (const float*)d_in[8];
  const float* Whh = (const float*)d_in[9];
  const float* bih = (const float*)d_in[10];
  const float* bhh = (const float*)d_in[11];
  const float* Wlin = (const float*)d_in[12];
  const float* blin = (const float*)d_in[13];
  const int* src = eidx;
  const int* dst = eidx + ETOT;

  char* ws = (char*)d_ws;
  unsigned short* Xt0 = (unsigned short*)ws;                  // 67,108,864
  unsigned short* Xt1 = (unsigned short*)(ws + 67108864);     // 67,108,864
  unsigned short* Db  = (unsigned short*)(ws + 134217728);    // 65,011,712 (seq bf16)
  float* xg = (float*)(ws + 199229440);                       // 100,663,296
  char* S = ws + 299892736;
  float* deg = (float*)S;                                     // 32768
  float* wn = (float*)(S + 32768);                            // 507904
  float* Lf = (float*)(S + 540672);                           // 2097152
  unsigned short* Lb = (unsigned short*)(S + 2637824);        // 1048576
  unsigned short* M2b = (unsigned short*)(S + 3686400);       // 1048576
  unsigned short* Wihb = (unsigned short*)(S + 4734976);      // 6094848
  unsigned short* Whhb = (unsigned short*)(S + 10829824);     // 1572864
  float* hf = (float*)(S + 12402688);                         // 262144
  unsigned short* hbA = (unsigned short*)(S + 12664832);      // 131072
  unsigned short* hbB = (unsigned short*)(S + 12795904);      // 131072
  unsigned int* flags = (unsigned int*)(S + 12926976);        // 1024

  if (ws_size < 312820736) return;

  hipMemsetAsync(deg, 0, 32768, stream);
  hipMemsetAsync(Lf, 0, 2097152, stream);
  hipMemsetAsync(hbA, 0, 131072, stream);
  hipMemsetAsync(flags, 0, 1024, stream);

  k_deg<<<ETOT / 256, 256, 0, stream>>>(src, ew, deg);
  k_wn<<<ETOT / 256, 256, 0, stream>>>(src, dst, ew, deg, wn);
  k_ldense<<<ETOT / 256, 256, 0, stream>>>(src, dst, wn, Lf);
  k_m2<<<NB, 256, 0, stream>>>(Lf, Lb, M2b);
  k_xt<<<NB * 32, 256, 0, stream>>>(x, Xt0);

  // fused Chebyshev layers (dense per-graph L)
  k_cheb<1><<<NB * 32, 256, 0, stream>>>(Xt0, Lb, M2b, Wc1, bc1, Xt1);
  k_cheb<2><<<NB * 32, 256, 0, stream>>>(Xt1, Lb, M2b, Wc2, bc2, Db);

  // weight converts
  k_cvt<<<(G3 * DIM / 4 + 255) / 256, 256, 0, stream>>>(Wih, Wihb, G3 * DIM);
  k_cvt<<<(G3 * HID / 4 + 255) / 256, 256, 0, stream>>>(Whh, Whhb, G3 * HID);

  // xg = seq @ Wih^T + bih  (bf16 MFMA, fp32 accum/out)
  dim3 gg(MROWS / 128, G3 / 128);
  k_gemm_mfma<<<gg, 256, 0, stream>>>(Db, Wihb, bih, xg);

  // all 128 GRU steps in one persistent kernel
  k_gru_persistent<<<GRU_BLOCKS, 512, 0, stream>>>(xg, Whhb, bhh, hbA, hbB, hf, flags);

  k_final<<<NB, 256, 0, stream>>>(hf, Wlin, blin, (float*)d_out);
}